// Round 10
// baseline (4126.363 us; speedup 1.0000x reference)
//
#include <hip/hip_runtime.h>

typedef _Float16 f16;
typedef f16    half8 __attribute__((ext_vector_type(8)));
typedef float  f32x4 __attribute__((ext_vector_type(4)));
typedef double f64x4 __attribute__((ext_vector_type(4)));

#define LDH 40   // padded halves per LDS row (16B-aligned rows, conflict-reducing)

// ---------------------------------------------------------------------------
// fp16 MFMA GEMM with k+1 register prefetch. C[M,N] = A[M,K]*B[K,N].
// MODE 0: f16 store; 1: f32 store; 2: f32 accumulate-add (non-atomic);
// MODE 3: f32 atomicAdd (for K-split). blockIdx.z = group*KS + kslice;
// each slice covers K/KS. KS=1 reproduces the R2-verified arithmetic exactly.
// M%128==0, (K/KS)%32==0, N%8==0.
// R2-verified staging (16B B-loads + scalar b16 transpose writes). R6's
// 4kx4n cell restage regressed +376us. Do not revisit.
// ---------------------------------------------------------------------------
template <int MODE>
__global__ __launch_bounds__(256) void gemm_h(
    const f16* __restrict__ A, const f16* __restrict__ Bg, void* __restrict__ Cg,
    int M, int K, int N, int ldc, long long sB, long long sC, int KS)
{
    const int gz   = blockIdx.z / KS;
    const int sl   = blockIdx.z - gz * KS;
    const int Ks   = K / KS;
    const int kbeg = sl * Ks;

    const f16* B = Bg + (size_t)gz * sB;

    __shared__ f16 Ah[128][LDH];
    __shared__ f16 Bt[128][LDH];   // B transposed: Bt[n][k ^ swz(n)]

    const int tid  = threadIdx.x;
    const int lane = tid & 63;
    const int wv   = tid >> 6;
    const int wm   = wv >> 1, wn = wv & 1;
    const int ln   = lane & 15;
    const int q    = lane >> 4;

    const int row0 = blockIdx.y * 128;
    const int col0 = blockIdx.x * 128;

    const int am = tid >> 1;           // A-stage row 0..127
    const int ak = (tid & 1) << 4;     // A-stage k 0/16
    const int bk = tid >> 3;           // B-stage k 0..31
    const int bn = (tid & 7) << 4;     // B-stage col 0..112

    const f16* Arow = A + (size_t)(row0 + am) * K + kbeg + ak;
    const int  cb   = col0 + bn;

    f32x4 acc[4][4];
#pragma unroll
    for (int i = 0; i < 4; ++i)
#pragma unroll
        for (int j = 0; j < 4; ++j) acc[i][j] = (f32x4){0.f, 0.f, 0.f, 0.f};

    // prologue loads (k0 = 0)
    uint4 a0 = *(const uint4*)(Arow);
    uint4 a1 = *(const uint4*)(Arow + 8);
    uint4 b0 = make_uint4(0, 0, 0, 0), b1 = make_uint4(0, 0, 0, 0);
    {
        const f16* Brow = B + (size_t)(kbeg + bk) * N;
        if (cb + 8  <= N) b0 = *(const uint4*)(Brow + cb);
        if (cb + 16 <= N) b1 = *(const uint4*)(Brow + cb + 8);
    }

    for (int k0 = 0; k0 < Ks; k0 += 32) {
        __syncthreads();
        *(uint4*)&Ah[am][ak]     = a0;
        *(uint4*)&Ah[am][ak + 8] = a1;
        {
            const f16* h0 = (const f16*)&b0;
            const f16* h1 = (const f16*)&b1;
#pragma unroll
            for (int j = 0; j < 8; ++j) {
                int n = bn + j;
                Bt[n][bk ^ (((n >> 4) & 3) << 3)] = h0[j];
            }
#pragma unroll
            for (int j = 0; j < 8; ++j) {
                int n = bn + 8 + j;
                Bt[n][bk ^ (((n >> 4) & 3) << 3)] = h1[j];
            }
        }
        __syncthreads();

        // prefetch k0+32 (overlaps the MFMA block below)
        if (k0 + 32 < Ks) {
            a0 = *(const uint4*)(Arow + k0 + 32);
            a1 = *(const uint4*)(Arow + k0 + 40);
            const f16* Brow = B + (size_t)(kbeg + k0 + 32 + bk) * N;
            if (cb + 8  <= N) b0 = *(const uint4*)(Brow + cb);
            if (cb + 16 <= N) b1 = *(const uint4*)(Brow + cb + 8);
        }

        half8 af[4], bf[4];
#pragma unroll
        for (int i = 0; i < 4; ++i)
            af[i] = *(const half8*)&Ah[wm * 64 + i * 16 + ln][q * 8];
#pragma unroll
        for (int j = 0; j < 4; ++j) {
            const int nb = wn * 64 + j * 16 + ln;
            const int sw = ((wn * 4 + j) & 3) << 3;
            bf[j] = *(const half8*)&Bt[nb][(q * 8) ^ sw];
        }
#pragma unroll
        for (int i = 0; i < 4; ++i)
#pragma unroll
            for (int j = 0; j < 4; ++j)
                acc[i][j] = __builtin_amdgcn_mfma_f32_16x16x32_f16(af[i], bf[j], acc[i][j], 0, 0, 0);
    }

    const size_t zoff = (size_t)gz * sC;
#pragma unroll
    for (int i = 0; i < 4; ++i) {
#pragma unroll
        for (int j = 0; j < 4; ++j) {
            const int c = col0 + wn * 64 + j * 16 + ln;
            if (c < N) {
#pragma unroll
                for (int t = 0; t < 4; ++t) {
                    const int r = row0 + wm * 64 + i * 16 + q * 4 + t;
                    const size_t o = zoff + (size_t)r * ldc + c;
                    const float v = acc[i][j][t];
                    if (MODE == 0)      ((f16*)Cg)[o] = (f16)v;
                    else if (MODE == 1) ((float*)Cg)[o] = v;
                    else if (MODE == 2) ((float*)Cg)[o] += v;
                    else                atomicAdd(&((float*)Cg)[o], v);
                }
            }
        }
    }
}

// ---------------------------------------------------------------------------
// fp64 MFMA layout probe. One wave. Determines the gfx950 lane<->matrix
// mapping of v_mfma_f64_16x16x4 empirically (m89 lesson: never trust an
// unverified MFMA layout).
// tbl[l*12 + {0..3}] = mA,kA,nB,kB ; +{4..7} = i(l,r) ; +{8..11} = j(l,r)
// ---------------------------------------------------------------------------
__global__ void probe_f64_k(int* __restrict__ tbl) {
    int l = threadIdx.x & 63;
    f64x4 z = (f64x4){0.0, 0.0, 0.0, 0.0};
    f64x4 dA = __builtin_amdgcn_mfma_f64_16x16x4f64((double)l, 1.0, z, 0, 0, 0);
    f64x4 dB = __builtin_amdgcn_mfma_f64_16x16x4f64(1.0, (double)l, z, 0, 0, 0);
    int* t = tbl + l * 12;
    {
        int v = (int)dA[0];
        if ((v & 3) == 0) { t[0] = l & 15; t[1] = l >> 4; }
        else              { t[0] = l >> 2; t[1] = l & 3;  }
    }
    {
        int v = (int)dB[0];
        if ((v & 3) == 0) { t[2] = l & 15; t[3] = l >> 4; }
        else              { t[2] = l >> 2; t[3] = l & 3;  }
    }
#pragma unroll
    for (int r = 0; r < 4; ++r) {
        int vA = (int)dA[r];
        t[4 + r] = ((vA & 3) == 0) ? (vA - 96) / 4 : (vA - 6) / 16;
        int vB = (int)dB[r];
        t[8 + r] = ((vB & 3) == 0) ? (vB - 96) / 4 : (vB - 6) / 16;
    }
}

__device__ inline void loadA4(const float* p, double* d) {
    float4 v = *(const float4*)p;
    d[0] = v.x; d[1] = v.y; d[2] = v.z; d[3] = v.w;
}
__device__ inline void loadA4(const double* p, double* d) {
    double2 v0 = *(const double2*)p, v1 = *(const double2*)(p + 2);
    d[0] = v0.x; d[1] = v0.y; d[2] = v1.x; d[3] = v1.y;
}

// ---------------------------------------------------------------------------
// fp64 MFMA GEMM, 64x64 / BK16. R2-verified best config (f64 path converged:
// R4 wide tile, R5 BK32, R7 N-split all land 423-453 us / MfmaUtil 61-65%).
// Now used only for the e1 residual (accum=1).
// ---------------------------------------------------------------------------
#define LDD 66

template <typename TA>
__global__ __launch_bounds__(256) void gemm_f64(
    const TA* __restrict__ A, const double* __restrict__ Bg, double* __restrict__ Cg,
    const int* __restrict__ tbl,
    int M, int K, int N, long long sB, long long sC, int accum)
{
    const double* B = Bg + (size_t)blockIdx.z * sB;
    double*       C = Cg + (size_t)blockIdx.z * sC;

    __shared__ double As[16][LDD];   // As[k][m]
    __shared__ double Bs[16][LDD];   // Bs[k][n]

    const int tid  = threadIdx.x;
    const int lane = tid & 63;
    const int wv   = tid >> 6;       // wave 0..3 -> rows 16*wv..16*wv+15
    const int m0   = wv << 4;

    const int* tl = tbl + lane * 12;
    const int mA = tl[0], kA = tl[1], nB = tl[2], kB = tl[3];
    int iT[4], jT[4];
#pragma unroll
    for (int r = 0; r < 4; ++r) { iT[r] = tl[4 + r]; jT[r] = tl[8 + r]; }

    const int row0 = blockIdx.y * 64;
    const int col0 = blockIdx.x * 64;

    const int ra = tid >> 2;          // A-stage row 0..63
    const int ka = (tid & 3) << 2;    // A-stage k 0,4,8,12
    const int kb = tid >> 4;          // B-stage k 0..15
    const int cb = (tid & 15) << 2;   // B-stage col 0..60

    const TA* Arow = A + (size_t)(row0 + ra) * K + ka;
    const int cbase = col0 + cb;

    f64x4 acc[4];
#pragma unroll
    for (int j = 0; j < 4; ++j) acc[j] = (f64x4){0.0, 0.0, 0.0, 0.0};

    double av[4];
    double2 bv0 = {0.0, 0.0}, bv1 = {0.0, 0.0};
    loadA4(Arow, av);
    if (cbase < N) {
        bv0 = *(const double2*)(B + (size_t)kb * N + cbase);
        bv1 = *(const double2*)(B + (size_t)kb * N + cbase + 2);
    }

    for (int k0 = 0; k0 < K; k0 += 16) {
        __syncthreads();
        As[ka + 0][ra] = av[0]; As[ka + 1][ra] = av[1];
        As[ka + 2][ra] = av[2]; As[ka + 3][ra] = av[3];
        *(double2*)&Bs[kb][cb]     = bv0;
        *(double2*)&Bs[kb][cb + 2] = bv1;
        __syncthreads();

        if (k0 + 16 < K) {
            loadA4(Arow + k0 + 16, av);
            if (cbase < N) {
                bv0 = *(const double2*)(B + (size_t)(k0 + 16 + kb) * N + cbase);
                bv1 = *(const double2*)(B + (size_t)(k0 + 16 + kb) * N + cbase + 2);
            }
        }

#pragma unroll
        for (int kq = 0; kq < 4; ++kq) {
            const double a = As[(kq << 2) + kA][m0 + mA];
#pragma unroll
            for (int j = 0; j < 4; ++j) {
                const double b = Bs[(kq << 2) + kB][(j << 4) + nB];
                acc[j] = __builtin_amdgcn_mfma_f64_16x16x4f64(a, b, acc[j], 0, 0, 0);
            }
        }
    }

#pragma unroll
    for (int j = 0; j < 4; ++j) {
#pragma unroll
        for (int r = 0; r < 4; ++r) {
            const int c = col0 + (j << 4) + jT[r];
            if (c < N) {
                const int rr = row0 + m0 + iT[r];
                double* p = C + (size_t)rr * N + c;
                double v = acc[j][r];
                if (accum) v += *p;
                *p = v;
            }
        }
    }
}

// ---------------------------------------------------------------------------
// fp64 3-term fused weight GEMM (R10): C = A0*B0 + A1*B1 + A2*B2, register
// accumulation over the concatenated K-range (same A0->A1->A2 order as the
// old store+RMW+RMW chain, so results differ by <=1 ulp). Eliminates the
// 2 f64 C read-modify-write passes per conv (~600 MB HBM total).
// Same BK16 / 64x64 schedule and probe-table mapping as gemm_f64.
// M%64==0, K%16==0 (per matrix), N%4==0. Pointer select via ternary
// (cndmask), not runtime-indexed array (avoids scratch spill).
// ---------------------------------------------------------------------------
__global__ __launch_bounds__(256) void gemm_f64w3(
    const double* __restrict__ A0g, const double* __restrict__ A1g, const double* __restrict__ A2g,
    const double* __restrict__ B0g, const double* __restrict__ B1g, const double* __restrict__ B2g,
    double* __restrict__ C, const int* __restrict__ tbl,
    int M, int K, int N)
{
    (void)M;
    __shared__ double As[16][LDD];   // As[k][m]
    __shared__ double Bs[16][LDD];   // Bs[k][n]

    const int tid  = threadIdx.x;
    const int lane = tid & 63;
    const int wv   = tid >> 6;
    const int m0   = wv << 4;

    const int* tl = tbl + lane * 12;
    const int mA = tl[0], kA = tl[1], nB = tl[2], kB = tl[3];
    int iT[4], jT[4];
#pragma unroll
    for (int r = 0; r < 4; ++r) { iT[r] = tl[4 + r]; jT[r] = tl[8 + r]; }

    const int row0 = blockIdx.y * 64;
    const int col0 = blockIdx.x * 64;

    const int ra = tid >> 2;          // A-stage row 0..63
    const int ka = (tid & 3) << 2;    // A-stage k 0,4,8,12
    const int kb = tid >> 4;          // B-stage k 0..15
    const int cb = (tid & 15) << 2;   // B-stage col 0..60

    const size_t aoff = (size_t)(row0 + ra) * K + ka;
    const double* Ar0 = A0g + aoff;
    const double* Ar1 = A1g + aoff;
    const double* Ar2 = A2g + aoff;
    const int cbase = col0 + cb;

    f64x4 acc[4];
#pragma unroll
    for (int j = 0; j < 4; ++j) acc[j] = (f64x4){0.0, 0.0, 0.0, 0.0};

    const int KT = 3 * K;
    double av[4];
    double2 bv0 = {0.0, 0.0}, bv1 = {0.0, 0.0};
    loadA4(Ar0, av);
    if (cbase < N) {
        const double* Brow = B0g + (size_t)kb * N + cbase;
        bv0 = *(const double2*)Brow;
        bv1 = *(const double2*)(Brow + 2);
    }

    for (int kt = 0; kt < KT; kt += 16) {
        __syncthreads();
        As[ka + 0][ra] = av[0]; As[ka + 1][ra] = av[1];
        As[ka + 2][ra] = av[2]; As[ka + 3][ra] = av[3];
        *(double2*)&Bs[kb][cb]     = bv0;
        *(double2*)&Bs[kb][cb + 2] = bv1;
        __syncthreads();

        // prefetch next k-tile (may cross matrix boundary)
        const int nt = kt + 16;
        if (nt < KT) {
            const int m    = (nt >= 2 * K) ? 2 : ((nt >= K) ? 1 : 0);
            const int koff = nt - m * K;
            const double* Ap = (m == 0) ? Ar0 : ((m == 1) ? Ar1 : Ar2);
            const double* Bp = (m == 0) ? B0g : ((m == 1) ? B1g : B2g);
            loadA4(Ap + koff, av);
            if (cbase < N) {
                const double* Brow = Bp + (size_t)(koff + kb) * N + cbase;
                bv0 = *(const double2*)Brow;
                bv1 = *(const double2*)(Brow + 2);
            }
        }

#pragma unroll
        for (int kq = 0; kq < 4; ++kq) {
            const double a = As[(kq << 2) + kA][m0 + mA];
#pragma unroll
            for (int j = 0; j < 4; ++j) {
                const double b = Bs[(kq << 2) + kB][(j << 4) + nB];
                acc[j] = __builtin_amdgcn_mfma_f64_16x16x4f64(a, b, acc[j], 0, 0, 0);
            }
        }
    }

#pragma unroll
    for (int j = 0; j < 4; ++j) {
#pragma unroll
        for (int r = 0; r < 4; ++r) {
            const int c = col0 + (j << 4) + jT[r];
            if (c < N) {
                const int rr = row0 + m0 + iT[r];
                C[(size_t)rr * N + c] = acc[j][r];
            }
        }
    }
}

// ---------------------------------------------------------------------------
// fp64 MFMA GEMM, 64x32 N-split variant (big L0/L1 GEMMs). R7-measured best
// total. Grid 1536 = 6 blocks/CU. Bit-identical k-summation order.
// ---------------------------------------------------------------------------
__global__ __launch_bounds__(256) void gemm_f64n(
    const float* __restrict__ A, const double* __restrict__ Bg, double* __restrict__ Cg,
    const int* __restrict__ tbl,
    int M, int K, int N, long long sB, long long sC)
{
    const double* B = Bg + (size_t)blockIdx.z * sB;
    double*       C = Cg + (size_t)blockIdx.z * sC;

    __shared__ double As[16][66];   // As[k][m]
    __shared__ double Bs[16][34];   // Bs[k][n], 32 cols + pad

    const int tid  = threadIdx.x;
    const int lane = tid & 63;
    const int wv   = tid >> 6;       // wave 0..3 -> rows 16*wv..16*wv+15
    const int m0   = wv << 4;

    const int* tl = tbl + lane * 12;
    const int mA = tl[0], kA = tl[1], nB = tl[2], kB = tl[3];
    int iT[4], jT[4];
#pragma unroll
    for (int r = 0; r < 4; ++r) { iT[r] = tl[4 + r]; jT[r] = tl[8 + r]; }

    const int row0 = blockIdx.y * 64;
    const int col0 = blockIdx.x * 32;

    const int ra = tid >> 2;          // A-stage row 0..63
    const int ka = (tid & 3) << 2;    // A-stage k 0,4,8,12
    const int kb = tid >> 4;          // B-stage k 0..15
    const int cb = (tid & 15) << 1;   // B-stage col 0,2,..,30

    const float* Arow = A + (size_t)(row0 + ra) * K + ka;
    const int cbase = col0 + cb;

    f64x4 acc[2];
#pragma unroll
    for (int j = 0; j < 2; ++j) acc[j] = (f64x4){0.0, 0.0, 0.0, 0.0};

    double av[4];
    double2 bv = {0.0, 0.0};
    loadA4(Arow, av);
    if (cbase < N) bv = *(const double2*)(B + (size_t)kb * N + cbase);

    for (int k0 = 0; k0 < K; k0 += 16) {
        __syncthreads();
        As[ka + 0][ra] = av[0]; As[ka + 1][ra] = av[1];
        As[ka + 2][ra] = av[2]; As[ka + 3][ra] = av[3];
        *(double2*)&Bs[kb][cb] = bv;
        __syncthreads();

        // prefetch k0+16 (overlaps MFMA block)
        if (k0 + 16 < K) {
            loadA4(Arow + k0 + 16, av);
            if (cbase < N) bv = *(const double2*)(B + (size_t)(k0 + 16 + kb) * N + cbase);
        }

#pragma unroll
        for (int kq = 0; kq < 4; ++kq) {
            const double a = As[(kq << 2) + kA][m0 + mA];
#pragma unroll
            for (int j = 0; j < 2; ++j) {
                const double b = Bs[(kq << 2) + kB][(j << 4) + nB];
                acc[j] = __builtin_amdgcn_mfma_f64_16x16x4f64(a, b, acc[j], 0, 0, 0);
            }
        }
    }

#pragma unroll
    for (int j = 0; j < 2; ++j) {
#pragma unroll
        for (int r = 0; r < 4; ++r) {
            const int c = col0 + (j << 4) + jT[r];
            if (c < N) {
                const int rr = row0 + m0 + iT[r];
                C[(size_t)rr * N + c] = acc[j][r];
            }
        }
    }
}

// ---------------------------------------------------------------------------
// Aux kernels. Activation layout: [g=4][node][b=8][C].
// ---------------------------------------------------------------------------
__global__ void zero_k(float* __restrict__ p, int n) {
    int i = blockIdx.x * blockDim.x + threadIdx.x;
    if (i < n) p[i] = 0.f;
}

__global__ void cast16_k(const float* __restrict__ s, f16* __restrict__ d, int n) {
    int i = blockIdx.x * blockDim.x + threadIdx.x;
    if (i < n) d[i] = (f16)s[i];
}

// x [32][3072][32] fp32 -> XT64 [g][n][bi][32] fp64
__global__ void regroup_in64_k(const float* __restrict__ x, double* __restrict__ XT, int total) {
    int i = blockIdx.x * blockDim.x + threadIdx.x;
    if (i >= total) return;
    int c = i & 31;
    int t = i >> 5;
    int n = t % 3072;
    int b = t / 3072;
    XT[((((size_t)(b >> 3) * 3072 + n) << 3) + (b & 7)) * 32 + c] = (double)x[i];
}

// fp16 combine: wa=w0-w2, wb=w1, wc=2*w2
__global__ void cheb_combine16_k(const float* __restrict__ w, f16* __restrict__ wa,
                                 f16* __restrict__ wb, f16* __restrict__ wc, int n) {
    int i = blockIdx.x * blockDim.x + threadIdx.x;
    if (i >= n) return;
    float w0 = w[i], w1 = w[n + i], w2 = w[2 * n + i];
    wa[i] = (f16)(w0 - w2); wb[i] = (f16)w1; wc[i] = (f16)(2.f * w2);
}
// fp64 combine (encoder)
__global__ void cheb_combine64_k(const float* __restrict__ w, double* __restrict__ wa,
                                 double* __restrict__ wb, double* __restrict__ wc, int n) {
    int i = blockIdx.x * blockDim.x + threadIdx.x;
    if (i >= n) return;
    double w0 = w[i], w1 = w[n + i], w2 = w[2 * n + i];
    wa[i] = w0 - w2; wb[i] = w1; wc[i] = 2.0 * w2;
}

__global__ void transpose_w16_k(const float* __restrict__ w, f16* __restrict__ wt, int R, int Ccol) {
    int i = blockIdx.x * blockDim.x + threadIdx.x;
    if (i >= R * Ccol) return;
    int r = i / Ccol, c = i - r * Ccol;
    wt[(size_t)c * R + r] = (f16)w[i];
}
__global__ void transpose_w64_k(const float* __restrict__ w, double* __restrict__ wt, int R, int Ccol) {
    int i = blockIdx.x * blockDim.x + threadIdx.x;
    if (i >= R * Ccol) return;
    int r = i / Ccol, c = i - r * Ccol;
    wt[(size_t)c * R + r] = (double)w[i];
}

// fp32 BN (stats; apply in-place + optional f16 mirror)
__global__ void bn_reduce_k(const float* __restrict__ X, float* __restrict__ stats,
                            int rows, int ld, int off) {
    int c = threadIdx.x;
    float s = 0.f, s2 = 0.f;
    for (int r = blockIdx.x; r < rows; r += gridDim.x) {
        float v = X[(size_t)r * ld + off + c];
        s += v; s2 += v * v;
    }
    atomicAdd(&stats[c], s);
    atomicAdd(&stats[256 + c], s2);
}
__global__ void bn_apply_k(float* X, const float* __restrict__ stats,
                           const float* __restrict__ g, const float* __restrict__ be,
                           const float* rbias, f16* mirror,
                           int total, int C, float invN, int ld, int off) {
    int i = blockIdx.x * blockDim.x + threadIdx.x;
    if (i >= total) return;
    int c = i % C;
    int row = i / C;
    size_t a = (size_t)row * ld + off + c;
    float mu = stats[c] * invN;
    float var = stats[256 + c] * invN - mu * mu;
    float sc = g[c] * rsqrtf(var + 1e-5f);
    float v = (X[a] - mu) * sc + be[c];
    v = fmaxf(v, 0.f);
    if (rbias) v += rbias[c];
    X[a] = v;
    if (mirror) mirror[a] = (f16)v;
}

// fp64 BN (encoder)
__global__ void bn_reduce64_k(const double* __restrict__ X, double* __restrict__ stats,
                              int rows, int ld) {
    int c = threadIdx.x;
    double s = 0.0, s2 = 0.0;
    for (int r = blockIdx.x; r < rows; r += gridDim.x) {
        double v = X[(size_t)r * ld + c];
        s += v; s2 += v * v;
    }
    atomicAdd(&stats[c], s);
    atomicAdd(&stats[256 + c], s2);
}
__global__ void bn_apply64_k(double* X, const double* __restrict__ stats,
                             const float* __restrict__ g, const float* __restrict__ be,
                             const float* rbias, int total, int C, double invN) {
    int i = blockIdx.x * blockDim.x + threadIdx.x;
    if (i >= total) return;
    int c = i % C;
    double mu = stats[c] * invN;
    double var = stats[256 + c] * invN - mu * mu;
    double sc = (double)g[c] / sqrt(var + 1e-5);
    double v = (X[i] - mu) * sc + (double)be[c];
    v = v > 0.0 ? v : 0.0;
    if (rbias) v += (double)rbias[c];
    X[i] = v;
}

// fp64 e1 [row][128] -> CATh high half (f16, ld 256, off 128)
__global__ void cast_e1_k(const double* __restrict__ E1, f16* __restrict__ cat, int total) {
    int i = blockIdx.x * blockDim.x + threadIdx.x;
    if (i >= total) return;
    int c = i & 127;
    int row = i >> 7;
    cat[(size_t)row * 256 + 128 + c] = (f16)E1[i];
}

// pool 4 consecutive nodes of fp64 e1 -> Ph f16 [g][q][b][128], IDX node index
__global__ void pool4_64_k(const double* __restrict__ e1, f16* __restrict__ p,
                           int* __restrict__ idx, int total) {
    int i = blockIdx.x * blockDim.x + threadIdx.x;
    if (i >= total) return;
    int c = i & 127;
    int t = i >> 7;
    int b = t & 7;
    t >>= 3;
    int q = t % 768;
    int g = t / 768;
    size_t base = ((((size_t)g * 3072 + 4 * q) << 3) + b) * 128 + c;
    double best = e1[base];
    int bj = 0;
#pragma unroll
    for (int j = 1; j < 4; ++j) {
        double v = e1[base + (size_t)j * 1024];
        if (v > best) { best = v; bj = j; }   // strict >: first occurrence (jnp.argmax)
    }
    p[i] = (f16)best;
    idx[i] = 4 * q + bj;
}

// scatter e2 (fp32) into CATh low half (f16)
__global__ void unpool_cat_k(const float* __restrict__ e2, const int* __restrict__ idx,
                             f16* __restrict__ cat, int total) {
    int i = blockIdx.x * blockDim.x + threadIdx.x;
    if (i >= total) return;
    int c = i & 127;
    int t = i >> 7;
    int b = t & 7;
    t >>= 3;
    int q = t % 768;
    int g = t / 768;
    f16 val = (f16)e2[i];
    int id = idx[i];
    size_t base = ((((size_t)g * 3072 + 4 * q) << 3) + b) * 256 + c;
#pragma unroll
    for (int j = 0; j < 4; ++j)
        cat[base + (size_t)j * 2048] = (4 * q + j == id) ? val : (f16)0.f;
}

// O [g][n][bi][8] fp32 -> out [B][N][8], + bias
__global__ void transpose_out_k(const float* __restrict__ O, const float* __restrict__ bias,
                                float* __restrict__ out, int total) {
    int i = blockIdx.x * blockDim.x + threadIdx.x;
    if (i >= total) return;
    int c = i & 7;
    int t = i >> 3;
    int n = t % 3072;
    int b = t / 3072;
    out[i] = O[((((size_t)(b >> 3) * 3072 + n) << 3) + (b & 7)) * 8 + c] + bias[c];
}

// ---------------------------------------------------------------------------
extern "C" void kernel_launch(void* const* d_in, const int* in_sizes, int n_in,
                              void* d_out, int out_size, void* d_ws, size_t ws_size,
                              hipStream_t stream)
{
    (void)in_sizes; (void)n_in; (void)out_size; (void)ws_size;

    const float* x    = (const float*)d_in[0];
    const float* L0   = (const float*)d_in[1];
    const float* L1   = (const float*)d_in[2];
    const float* w11  = (const float*)d_in[3];
    const float* g11  = (const float*)d_in[5];
    const float* be11 = (const float*)d_in[6];
    const float* w13  = (const float*)d_in[7];
    const float* g13  = (const float*)d_in[9];
    const float* be13 = (const float*)d_in[10];
    const float* wr1  = (const float*)d_in[11];
    const float* br1  = (const float*)d_in[12];
    const float* w21  = (const float*)d_in[13];
    const float* g21  = (const float*)d_in[15];
    const float* be21 = (const float*)d_in[16];
    const float* w23  = (const float*)d_in[17];
    const float* g23  = (const float*)d_in[19];
    const float* be23 = (const float*)d_in[20];
    const float* wr2  = (const float*)d_in[21];
    const float* br2  = (const float*)d_in[22];
    const float* uw11 = (const float*)d_in[23];
    const float* ug11 = (const float*)d_in[25];
    const float* ube11= (const float*)d_in[26];
    const float* uw12 = (const float*)d_in[27];
    const float* ug12 = (const float*)d_in[29];
    const float* ube12= (const float*)d_in[30];
    const float* uwr1 = (const float*)d_in[31];
    const float* ubr1 = (const float*)d_in[32];
    const float* uw13 = (const float*)d_in[33];
    const float* ub13 = (const float*)d_in[34];
    float* out = (float*)d_out;

    float* ws = (float*)d_ws;
    size_t off = 0;
    auto alloc = [&](size_t n) { float* p = ws + off; off += (n + 63) & ~(size_t)63; return p; };

    // ---- regions (floats). Total ~224 MiB. ----
    float* R1 = alloc(12582912);   // CATh f16[25165824] | p1: H1 dbl[6291456]
    float* R2 = alloc(25165824);   // D1 fp32 + H64 fp32 + T1h/T2h f16 | p1: E1 dbl[12582912]
    float* R3 = alloc(6291456);    // p1: XT64 dbl[3145728] | p2: H2h f16 then D1h f16
    float* R4 = alloc(6291456);    // p1: T1d dbl[3145728] | p2: Ph f16 + H64h f16
    int*  IDX = (int*)alloc(3145728);  // p1 (with L0f): T2d dbl[3145728]
    float* L0f = alloc(4718592);   // p2: L0h f16[9437184]
    float* L1f = alloc(294912);    // p2: L1h f16[589824]
    float* ST  = alloc(1536);      // fp32 stats [0..512), fp64 stats [512..1536)
    int*  TBL  = (int*)alloc(768); // f64-MFMA layout table (64 lanes x 12 ints)

    // f16 weights
    f16* wa21h = (f16*)alloc(12288); f16* wb21h = (f16*)alloc(12288); f16* wc21h = (f16*)alloc(12288);
    f16* wa23h = (f16*)alloc(12288); f16* wb23h = (f16*)alloc(12288); f16* wc23h = (f16*)alloc(12288);
    f16* wau11h = (f16*)alloc(16384); f16* wbu11h = (f16*)alloc(16384); f16* wcu11h = (f16*)alloc(16384);
    f16* wau12h = (f16*)alloc(4096);  f16* wbu12h = (f16*)alloc(4096);  f16* wcu12h = (f16*)alloc(4096);
    f16* wau13h = (f16*)alloc(256);   f16* wbu13h = (f16*)alloc(256);   f16* wcu13h = (f16*)alloc(256);
    f16* wr2Th  = (f16*)alloc(8192);
    f16* uwr1Th = (f16*)alloc(8192);

    // fp64 weights (encoder)
    double* wa11_64 = (double*)alloc(4096);
    double* wb11_64 = (double*)alloc(4096);
    double* wc11_64 = (double*)alloc(4096);
    double* wa13_64 = (double*)alloc(16384);
    double* wb13_64 = (double*)alloc(16384);
    double* wc13_64 = (double*)alloc(16384);
    double* wr1T_64 = (double*)alloc(8192);

    // ---- aliases ----
    f16*    CATh = (f16*)R1;
    double* H1   = (double*)R1;
    float*  D1   = R2;                       // [g][n][b][128] fp32
    float*  H2   = R2;                       // [g][q][b][192] fp32
    float*  Y3   = R2 + 4718592;             // [g][q][b][128] fp32
    float*  O    = R2;                       // final [g][n][b][8] fp32
    float*  H64  = R2 + 12582912;            // [g][n][b][64] fp32
    f16*    T1h  = (f16*)(R2 + 18874368);    // f16[6291456]
    f16*    T2h  = (f16*)(R2 + 22020096);    // f16[6291456]
    f16*    TCMB = T1h;                      // T1h+T2h contiguous: f16[12582912] (dec1 z=4 merge)
    double* E1   = (double*)R2;              // dbl[12582912] spans R2
    double* XT64 = (double*)R3;
    f16*    H2h  = (f16*)R3;                 // early phase-2
    f16*    D1h  = (f16*)R3;                 // late phase-2 (H2h dead)
    double* T1d  = (double*)R4;              // dbl[3145728]
    double* T2d  = (double*)IDX;             // dbl[3145728] spanning IDX + L0f front half
    f16*    Ph   = (f16*)R4;                 // f16[3145728] (phase 2)
    f16*    H64h = (f16*)(R4 + 1572864);     // f16[6291456] (phase 2)
    f16*    L0h  = (f16*)L0f;
    f16*    L1h  = (f16*)L1f;
    double* ST64 = (double*)(ST + 512);
    // reassociated-decoder scratch (all dead-slot reuse, no new allocs):
    float*  RFa  = H64;                      // final-conv R fp32
    float*  RFb  = R2;                       // dec1/dec2 R fp32 (D1-slot time-share)
    float*  FSCR = H64;                      // L2-conv K-split f32 scratch (H64 free then)

    auto gh = [&](int mode, const f16* A, const f16* B, void* C, int M, int K, int N,
                  int ldc, long long sB, long long sC, int z, int ks) {
        dim3 grid((N + 127) / 128, M / 128, z * ks);
        if (mode == 0)      gemm_h<0><<<grid, 256, 0, stream>>>(A, B, C, M, K, N, ldc, sB, sC, ks);
        else if (mode == 1) gemm_h<1><<<grid, 256, 0, stream>>>(A, B, C, M, K, N, ldc, sB, sC, ks);
        else if (mode == 2) gemm_h<2><<<grid, 256, 0, stream>>>(A, B, C, M, K, N, ldc, sB, sC, ks);
        else                gemm_h<3><<<grid, 256, 0, stream>>>(A, B, C, M, K, N, ldc, sB, sC, ks);
    };
    // big L GEMMs: 64x32 N-split tile (grid 1536 = 6 blocks/CU)
    auto gemm64f = [&](const float* A, const double* B, double* C, int M, int K, int N,
                       long long sB, long long sC, int z) {
        dim3 grid((N + 31) / 32, M / 64, z);
        gemm_f64n<<<grid, 256, 0, stream>>>(A, B, C, TBL, M, K, N, sB, sC);
    };
    auto gemm64d = [&](const double* A, const double* B, double* C, int M, int K, int N, int accum) {
        dim3 grid((N + 63) / 64, M / 64);
        gemm_f64<double><<<grid, 256, 0, stream>>>(A, B, C, TBL, M, K, N, 0, 0, accum);
    };
    auto gemm64w3 = [&](const double* A0, const double* A1, const double* A2,
                        const double* B0, const double* B1, const double* B2,
                        double* C, int M, int K, int N) {
        dim3 grid((N + 63) / 64, M / 64);
        gemm_f64w3<<<grid, 256, 0, stream>>>(A0, A1, A2, B0, B1, B2, C, TBL, M, K, N);
    };
    auto bn = [&](float* X, int rows, int C, int ld, int offc,
                  const float* gp, const float* bep, const float* rbias, f16* mirror) {
        zero_k<<<2, 256, 0, stream>>>(ST, 512);
        bn_reduce_k<<<384, C, 0, stream>>>(X, ST, rows, ld, offc);
        int total = rows * C;
        bn_apply_k<<<(total + 255) / 256, 256, 0, stream>>>(
            X, ST, gp, bep, rbias, mirror, total, C, 1.f / (float)rows, ld, offc);
    };
    auto bn64 = [&](double* X, int rows, int C,
                    const float* gp, const float* bep, const float* rbias) {
        zero_k<<<4, 256, 0, stream>>>(ST + 512, 1024);
        bn_reduce64_k<<<384, C, 0, stream>>>(X, ST64, rows, C);
        int total = rows * C;
        bn_apply64_k<<<(total + 255) / 256, 256, 0, stream>>>(
            X, ST64, gp, bep, rbias, total, C, 1.0 / (double)rows);
    };
    auto comb16 = [&](const float* w, f16* a, f16* b, f16* c, int n) {
        cheb_combine16_k<<<(n + 255) / 256, 256, 0, stream>>>(w, a, b, c, n);
    };

    // ---- f64-MFMA layout probe (must precede all gemm_f64 launches) ----
    probe_f64_k<<<1, 64, 0, stream>>>(TBL);

    // ---- fp64 weight prep + input regroup ----
    cheb_combine64_k<<<8, 256, 0, stream>>>(w11, wa11_64, wb11_64, wc11_64, 2048);
    cheb_combine64_k<<<32, 256, 0, stream>>>(w13, wa13_64, wb13_64, wc13_64, 8192);
    transpose_w64_k<<<16, 256, 0, stream>>>(wr1, wr1T_64, 128, 32);
    regroup_in64_k<<<12288, 256, 0, stream>>>(x, XT64, 3145728);

    // ==== PHASE 1 (fp64 MFMA): encoder to e1, exact argmax ====
    // conv1: 32 -> 64, z=4 batched (T1d/T2d = [4][3072][256] dbl)
    // R10: 3-term fused weight GEMM (register accumulation, no C RMW).
    gemm64f(L0, XT64, T1d, 3072, 3072, 256, 786432, 786432, 4);
    gemm64f(L0, T1d, T2d, 3072, 3072, 256, 786432, 786432, 4);
    gemm64w3(XT64, T1d, T2d, wa11_64, wb11_64, wc11_64, H1, 98304, 32, 64);
    bn64(H1, 98304, 64, g11, be11, nullptr);                 // h1

    // conv2: 64 -> 128, two z=2 halves (T1d/T2d = [2][3072][512] dbl)
    for (int h = 0; h < 2; ++h) {
        const double* Hh = H1 + (size_t)h * 3145728;
        double*       Eh = E1 + (size_t)h * 6291456;
        gemm64f(L0, Hh, T1d, 3072, 3072, 512, 1572864, 1572864, 2);
        gemm64f(L0, T1d, T2d, 3072, 3072, 512, 1572864, 1572864, 2);
        gemm64w3(Hh, T1d, T2d, wa13_64, wb13_64, wc13_64, Eh, 49152, 64, 128);
    }
    bn64(E1, 98304, 128, g13, be13, br1);
    gemm64d(XT64, wr1T_64, E1, 98304, 32, 128, 1);           // e1 (fp64, RMW residual)

    // ---- f16 weight prep (delayed: L0f/IDX regions were phase-1 scratch) ----
    comb16(w21,  wa21h,  wb21h,  wc21h,  24576);
    comb16(w23,  wa23h,  wb23h,  wc23h,  24576);
    comb16(uw11, wau11h, wbu11h, wcu11h, 32768);
    comb16(uw12, wau12h, wbu12h, wcu12h, 8192);
    comb16(uw13, wau13h, wbu13h, wcu13h, 512);
    transpose_w16_k<<<64, 256, 0, stream>>>(wr2, wr2Th, 128, 128);
    transpose_w16_k<<<64, 256, 0, stream>>>(uwr1, uwr1Th, 64, 256);
    cast16_k<<<36864, 256, 0, stream>>>(L0, L0h, 9437184);
    cast16_k<<<2304, 256, 0, stream>>>(L1, L1h, 589824);

    // transition: pool on fp64; CATh high = f16(e1)
    pool4_64_k<<<12288, 256, 0, stream>>>(E1, Ph, IDX, 3145728);
    cast_e1_k<<<49152, 256, 0, stream>>>(E1, CATh, 12582912);
    // E1 / XT64 / H1 / T1d / T2d dead from here.

    // ==== PHASE 2 (fp16 MFMA) ====
    // L2 conv1: 128 -> 192. R10: L-GEMMs were 192 blocks = 1 wave/SIMD
    // (zero TLP); K-split x4 via MODE 3 into zeroed f32 scratch (FSCR =
    // dead H64 slot, no overlap with H2/Y3/T1h), then cast to f16.
    zero_k<<<12288, 256, 0, stream>>>(FSCR, 3145728);
    gh(3, L1h, Ph, FSCR, 768, 768, 1024, 1024, 786432, 786432, 4, 4);   // T1 f32 (768 blk)
    cast16_k<<<12288, 256, 0, stream>>>(FSCR, T1h, 3145728);
    zero_k<<<12288, 256, 0, stream>>>(FSCR, 3145728);
    gh(3, L1h, T1h, FSCR, 768, 768, 1024, 1024, 786432, 786432, 4, 4);  // T2 f32
    cast16_k<<<12288, 256, 0, stream>>>(FSCR, T2h, 3145728);
    gh(1, Ph,  wa21h, H2, 24576, 128, 192, 192, 0, 0, 1, 1);
    gh(2, T1h, wb21h, H2, 24576, 128, 192, 192, 0, 0, 1, 1);
    gh(2, T2h, wc21h, H2, 24576, 128, 192, 192, 0, 0, 1, 1);
    bn(H2, 24576, 192, 192, 0, g21, be21, nullptr, H2h);     // h2 (+f16 mirror)

    // L2 conv2: 192 -> 128, + residual -> e2 (Y3). Same K-split treatment
    // (was 288 blocks).
    zero_k<<<18432, 256, 0, stream>>>(FSCR, 4718592);
    gh(3, L1h, H2h, FSCR, 768, 768, 1536, 1536, 1179648, 1179648, 4, 4);  // T1 f32 (1152 blk)
    cast16_k<<<18432, 256, 0, stream>>>(FSCR, T1h, 4718592);
    zero_k<<<18432, 256, 0, stream>>>(FSCR, 4718592);
    gh(3, L1h, T1h, FSCR, 768, 768, 1536, 1536, 1179648, 1179648, 4, 4);  // T2 f32
    cast16_k<<<18432, 256, 0, stream>>>(FSCR, T2h, 4718592);
    gh(1, H2h, wa23h, Y3, 24576, 192, 128, 128, 0, 0, 1, 1);
    gh(2, T1h, wb23h, Y3, 24576, 192, 128, 128, 0, 0, 1, 1);
    gh(2, T2h, wc23h, Y3, 24576, 192, 128, 128, 0, 0, 1, 1);
    bn(Y3, 24576, 128, 128, 0, g23, be23, br2, nullptr);
    gh(2, Ph, wr2Th, Y3, 24576, 128, 128, 128, 0, 0, 1, 1);  // e2

    // unpool into CATh low (f16)
    unpool_cat_k<<<12288, 256, 0, stream>>>(Y3, IDX, CATh, 3145728);

    // dec conv1: 256 -> 128, REASSOCIATED, single z=4 pass (R8, 768-block
    // balanced). Buffers: P2->TCMB, R->D1 slot, Rh->TCMB, D->D1 slot.
    gh(0, CATh, wcu11h, TCMB, 98304, 256, 128, 128, 0, 0, 1, 1);            // P2 = cat*Wc (f16)
    gh(1, CATh, wbu11h, RFb, 98304, 256, 128, 128, 0, 0, 1, 1);             // R  = cat*Wb (f32)
    gh(2, L0h, TCMB, RFb, 3072, 3072, 1024, 1024, 3145728, 3145728, 4, 1);  // R += L*P2 (768 blk)
    cast16_k<<<49152, 256, 0, stream>>>(RFb, TCMB, 12582912);               // Rh = f16(R), P2 dead
    gh(1, CATh, wau11h, D1, 98304, 256, 128, 128, 0, 0, 1, 1);              // D  = cat*Wa (over R)
    gh(2, L0h, TCMB, D1, 3072, 3072, 1024, 1024, 3145728, 3145728, 4, 1);   // D += L*Rh
    bn(D1, 98304, 128, 128, 0, ug11, ube11, nullptr, D1h);   // d1 (+f16 mirror)

    // dec conv2: 128 -> 64, REASSOCIATED. R9: L-GEMMs K-split x2 via MODE 3
    // atomic (384 -> 768 blocks; weight GEMM stores first, no pre-zero).
    gh(0, D1h, wcu12h, T2h, 98304, 128, 64, 64, 0, 0, 1, 1);                // P2 = d1*Wc
    gh(1, D1h, wbu12h, RFb, 98304, 128, 64, 64, 0, 0, 1, 1);                // R  = d1*Wb
    gh(3, L0h, T2h, RFb, 3072, 3072, 512, 512, 1572864, 1572864, 4, 2);     // R += L*P2 (atomic)
    cast16_k<<<24576, 256, 0, stream>>>(RFb, T1h, 6291456);                 // Rh
    gh(1, D1h, wau12h, H64, 98304, 128, 64, 64, 0, 0, 1, 1);                // H64 = d1*Wa
    gh(3, L0h, T1h, H64, 3072, 3072, 512, 512, 1572864, 1572864, 4, 2);     // H64 += L*R (atomic)
    bn(H64, 98304, 64, 64, 0, ug12, ube12, ubr1, nullptr);
    gh(2, CATh, uwr1Th, H64, 98304, 256, 64, 64, 0, 0, 1, 1); // d2 = bn + residual
    cast16_k<<<24576, 256, 0, stream>>>(H64, H64h, 6291456);  // d2 f16 mirror (H64 fp32 dead)

    // final conv: 64 -> 8, REASSOCIATED. R9: L-GEMMs K-split x8 via MODE 3
    // atomic (96 -> 768 blocks; Ks=384).
    gh(0, H64h, wcu13h, T2h, 98304, 64, 8, 8, 0, 0, 1, 1);                  // P2 = d2*Wc
    gh(1, H64h, wbu13h, RFa, 98304, 64, 8, 8, 0, 0, 1, 1);                  // R  = d2*Wb
    gh(3, L0h, T2h, RFa, 3072, 3072, 64, 64, 196608, 196608, 4, 8);         // R += L*P2 (atomic)
    cast16_k<<<3072, 256, 0, stream>>>(RFa, T1h, 786432);                   // Rh
    gh(1, H64h, wau13h, O, 98304, 64, 8, 8, 0, 0, 1, 1);                    // O  = d2*Wa
    gh(3, L0h, T1h, O, 3072, 3072, 64, 64, 196608, 196608, 4, 8);           // O += L*R (atomic)

    transpose_out_k<<<3072, 256, 0, stream>>>(O, ub13, out, 786432);
}

// Round 11
// 3948.790 us; speedup vs baseline: 1.0450x; 1.0450x over previous
//
#include <hip/hip_runtime.h>

typedef _Float16 f16;
typedef f16    half8 __attribute__((ext_vector_type(8)));
typedef float  f32x4 __attribute__((ext_vector_type(4)));
typedef double f64x4 __attribute__((ext_vector_type(4)));

#define LDH 40   // padded halves per LDS row (16B-aligned rows, conflict-reducing)

// ---------------------------------------------------------------------------
// fp16 MFMA GEMM with k+1 register prefetch. C[M,N] = A[M,K]*B[K,N].
// MODE 0: f16 store; 1: f32 store; 2: f32 accumulate-add (non-atomic);
// MODE 3: f32 atomicAdd (for K-split). blockIdx.z = group*KS + kslice;
// each slice covers K/KS. KS=1 reproduces the R2-verified arithmetic exactly.
// M%128==0, (K/KS)%32==0, N%8==0.
// R2-verified staging (16B B-loads + scalar b16 transpose writes). R6's
// 4kx4n cell restage regressed +376us. Do not revisit.
// R11: K-split is used ONLY where the natural grid is <3 blocks/CU AND the
// work is large (dec2/final conv). R10's L2-conv K-split regressed +70us
// (zero/cast overhead on cache-resident small GEMMs). Do not revisit.
// ---------------------------------------------------------------------------
template <int MODE>
__global__ __launch_bounds__(256) void gemm_h(
    const f16* __restrict__ A, const f16* __restrict__ Bg, void* __restrict__ Cg,
    int M, int K, int N, int ldc, long long sB, long long sC, int KS)
{
    const int gz   = blockIdx.z / KS;
    const int sl   = blockIdx.z - gz * KS;
    const int Ks   = K / KS;
    const int kbeg = sl * Ks;

    const f16* B = Bg + (size_t)gz * sB;

    __shared__ f16 Ah[128][LDH];
    __shared__ f16 Bt[128][LDH];   // B transposed: Bt[n][k ^ swz(n)]

    const int tid  = threadIdx.x;
    const int lane = tid & 63;
    const int wv   = tid >> 6;
    const int wm   = wv >> 1, wn = wv & 1;
    const int ln   = lane & 15;
    const int q    = lane >> 4;

    const int row0 = blockIdx.y * 128;
    const int col0 = blockIdx.x * 128;

    const int am = tid >> 1;           // A-stage row 0..127
    const int ak = (tid & 1) << 4;     // A-stage k 0/16
    const int bk = tid >> 3;           // B-stage k 0..31
    const int bn = (tid & 7) << 4;     // B-stage col 0..112

    const f16* Arow = A + (size_t)(row0 + am) * K + kbeg + ak;
    const int  cb   = col0 + bn;

    f32x4 acc[4][4];
#pragma unroll
    for (int i = 0; i < 4; ++i)
#pragma unroll
        for (int j = 0; j < 4; ++j) acc[i][j] = (f32x4){0.f, 0.f, 0.f, 0.f};

    // prologue loads (k0 = 0)
    uint4 a0 = *(const uint4*)(Arow);
    uint4 a1 = *(const uint4*)(Arow + 8);
    uint4 b0 = make_uint4(0, 0, 0, 0), b1 = make_uint4(0, 0, 0, 0);
    {
        const f16* Brow = B + (size_t)(kbeg + bk) * N;
        if (cb + 8  <= N) b0 = *(const uint4*)(Brow + cb);
        if (cb + 16 <= N) b1 = *(const uint4*)(Brow + cb + 8);
    }

    for (int k0 = 0; k0 < Ks; k0 += 32) {
        __syncthreads();
        *(uint4*)&Ah[am][ak]     = a0;
        *(uint4*)&Ah[am][ak + 8] = a1;
        {
            const f16* h0 = (const f16*)&b0;
            const f16* h1 = (const f16*)&b1;
#pragma unroll
            for (int j = 0; j < 8; ++j) {
                int n = bn + j;
                Bt[n][bk ^ (((n >> 4) & 3) << 3)] = h0[j];
            }
#pragma unroll
            for (int j = 0; j < 8; ++j) {
                int n = bn + 8 + j;
                Bt[n][bk ^ (((n >> 4) & 3) << 3)] = h1[j];
            }
        }
        __syncthreads();

        // prefetch k0+32 (overlaps the MFMA block below)
        if (k0 + 32 < Ks) {
            a0 = *(const uint4*)(Arow + k0 + 32);
            a1 = *(const uint4*)(Arow + k0 + 40);
            const f16* Brow = B + (size_t)(kbeg + k0 + 32 + bk) * N;
            if (cb + 8  <= N) b0 = *(const uint4*)(Brow + cb);
            if (cb + 16 <= N) b1 = *(const uint4*)(Brow + cb + 8);
        }

        half8 af[4], bf[4];
#pragma unroll
        for (int i = 0; i < 4; ++i)
            af[i] = *(const half8*)&Ah[wm * 64 + i * 16 + ln][q * 8];
#pragma unroll
        for (int j = 0; j < 4; ++j) {
            const int nb = wn * 64 + j * 16 + ln;
            const int sw = ((wn * 4 + j) & 3) << 3;
            bf[j] = *(const half8*)&Bt[nb][(q * 8) ^ sw];
        }
#pragma unroll
        for (int i = 0; i < 4; ++i)
#pragma unroll
            for (int j = 0; j < 4; ++j)
                acc[i][j] = __builtin_amdgcn_mfma_f32_16x16x32_f16(af[i], bf[j], acc[i][j], 0, 0, 0);
    }

    const size_t zoff = (size_t)gz * sC;
#pragma unroll
    for (int i = 0; i < 4; ++i) {
#pragma unroll
        for (int j = 0; j < 4; ++j) {
            const int c = col0 + wn * 64 + j * 16 + ln;
            if (c < N) {
#pragma unroll
                for (int t = 0; t < 4; ++t) {
                    const int r = row0 + wm * 64 + i * 16 + q * 4 + t;
                    const size_t o = zoff + (size_t)r * ldc + c;
                    const float v = acc[i][j][t];
                    if (MODE == 0)      ((f16*)Cg)[o] = (f16)v;
                    else if (MODE == 1) ((float*)Cg)[o] = v;
                    else if (MODE == 2) ((float*)Cg)[o] += v;
                    else                atomicAdd(&((float*)Cg)[o], v);
                }
            }
        }
    }
}

// ---------------------------------------------------------------------------
// fp64 MFMA layout probe. One wave. Determines the gfx950 lane<->matrix
// mapping of v_mfma_f64_16x16x4 empirically (m89 lesson: never trust an
// unverified MFMA layout).
// tbl[l*12 + {0..3}] = mA,kA,nB,kB ; +{4..7} = i(l,r) ; +{8..11} = j(l,r)
// ---------------------------------------------------------------------------
__global__ void probe_f64_k(int* __restrict__ tbl) {
    int l = threadIdx.x & 63;
    f64x4 z = (f64x4){0.0, 0.0, 0.0, 0.0};
    f64x4 dA = __builtin_amdgcn_mfma_f64_16x16x4f64((double)l, 1.0, z, 0, 0, 0);
    f64x4 dB = __builtin_amdgcn_mfma_f64_16x16x4f64(1.0, (double)l, z, 0, 0, 0);
    int* t = tbl + l * 12;
    {
        int v = (int)dA[0];
        if ((v & 3) == 0) { t[0] = l & 15; t[1] = l >> 4; }
        else              { t[0] = l >> 2; t[1] = l & 3;  }
    }
    {
        int v = (int)dB[0];
        if ((v & 3) == 0) { t[2] = l & 15; t[3] = l >> 4; }
        else              { t[2] = l >> 2; t[3] = l & 3;  }
    }
#pragma unroll
    for (int r = 0; r < 4; ++r) {
        int vA = (int)dA[r];
        t[4 + r] = ((vA & 3) == 0) ? (vA - 96) / 4 : (vA - 6) / 16;
        int vB = (int)dB[r];
        t[8 + r] = ((vB & 3) == 0) ? (vB - 96) / 4 : (vB - 6) / 16;
    }
}

__device__ inline void loadA4(const float* p, double* d) {
    float4 v = *(const float4*)p;
    d[0] = v.x; d[1] = v.y; d[2] = v.z; d[3] = v.w;
}
__device__ inline void loadA4(const double* p, double* d) {
    double2 v0 = *(const double2*)p, v1 = *(const double2*)(p + 2);
    d[0] = v0.x; d[1] = v0.y; d[2] = v1.x; d[3] = v1.y;
}

// ---------------------------------------------------------------------------
// fp64 MFMA GEMM, 64x64 / BK16. R2-verified best config (f64 path converged:
// R4 wide tile, R5 BK32, R7 N-split all land 423-453 us / MfmaUtil 61-65%).
// Used only for the e1 residual (accum=1).
// ---------------------------------------------------------------------------
#define LDD 66

template <typename TA>
__global__ __launch_bounds__(256) void gemm_f64(
    const TA* __restrict__ A, const double* __restrict__ Bg, double* __restrict__ Cg,
    const int* __restrict__ tbl,
    int M, int K, int N, long long sB, long long sC, int accum)
{
    const double* B = Bg + (size_t)blockIdx.z * sB;
    double*       C = Cg + (size_t)blockIdx.z * sC;

    __shared__ double As[16][LDD];   // As[k][m]
    __shared__ double Bs[16][LDD];   // Bs[k][n]

    const int tid  = threadIdx.x;
    const int lane = tid & 63;
    const int wv   = tid >> 6;       // wave 0..3 -> rows 16*wv..16*wv+15
    const int m0   = wv << 4;

    const int* tl = tbl + lane * 12;
    const int mA = tl[0], kA = tl[1], nB = tl[2], kB = tl[3];
    int iT[4], jT[4];
#pragma unroll
    for (int r = 0; r < 4; ++r) { iT[r] = tl[4 + r]; jT[r] = tl[8 + r]; }

    const int row0 = blockIdx.y * 64;
    const int col0 = blockIdx.x * 64;

    const int ra = tid >> 2;          // A-stage row 0..63
    const int ka = (tid & 3) << 2;    // A-stage k 0,4,8,12
    const int kb = tid >> 4;          // B-stage k 0..15
    const int cb = (tid & 15) << 2;   // B-stage col 0..60

    const TA* Arow = A + (size_t)(row0 + ra) * K + ka;
    const int cbase = col0 + cb;

    f64x4 acc[4];
#pragma unroll
    for (int j = 0; j < 4; ++j) acc[j] = (f64x4){0.0, 0.0, 0.0, 0.0};

    double av[4];
    double2 bv0 = {0.0, 0.0}, bv1 = {0.0, 0.0};
    loadA4(Arow, av);
    if (cbase < N) {
        bv0 = *(const double2*)(B + (size_t)kb * N + cbase);
        bv1 = *(const double2*)(B + (size_t)kb * N + cbase + 2);
    }

    for (int k0 = 0; k0 < K; k0 += 16) {
        __syncthreads();
        As[ka + 0][ra] = av[0]; As[ka + 1][ra] = av[1];
        As[ka + 2][ra] = av[2]; As[ka + 3][ra] = av[3];
        *(double2*)&Bs[kb][cb]     = bv0;
        *(double2*)&Bs[kb][cb + 2] = bv1;
        __syncthreads();

        if (k0 + 16 < K) {
            loadA4(Arow + k0 + 16, av);
            if (cbase < N) {
                bv0 = *(const double2*)(B + (size_t)(k0 + 16 + kb) * N + cbase);
                bv1 = *(const double2*)(B + (size_t)(k0 + 16 + kb) * N + cbase + 2);
            }
        }

#pragma unroll
        for (int kq = 0; kq < 4; ++kq) {
            const double a = As[(kq << 2) + kA][m0 + mA];
#pragma unroll
            for (int j = 0; j < 4; ++j) {
                const double b = Bs[(kq << 2) + kB][(j << 4) + nB];
                acc[j] = __builtin_amdgcn_mfma_f64_16x16x4f64(a, b, acc[j], 0, 0, 0);
            }
        }
    }

#pragma unroll
    for (int j = 0; j < 4; ++j) {
#pragma unroll
        for (int r = 0; r < 4; ++r) {
            const int c = col0 + (j << 4) + jT[r];
            if (c < N) {
                const int rr = row0 + m0 + iT[r];
                double* p = C + (size_t)rr * N + c;
                double v = acc[j][r];
                if (accum) v += *p;
                *p = v;
            }
        }
    }
}

// ---------------------------------------------------------------------------
// fp64 3-term fused weight GEMM (R10, kept in R11): C = A0*B0 + A1*B1 +
// A2*B2, register accumulation over the concatenated K-range (same
// A0->A1->A2 order as the old store+RMW+RMW chain, <=1 ulp difference).
// Strictly less work than the 3-dispatch chain: same k-tile count, one
// launch, no C read-modify-write. Same BK16 / 64x64 schedule.
// ---------------------------------------------------------------------------
__global__ __launch_bounds__(256) void gemm_f64w3(
    const double* __restrict__ A0g, const double* __restrict__ A1g, const double* __restrict__ A2g,
    const double* __restrict__ B0g, const double* __restrict__ B1g, const double* __restrict__ B2g,
    double* __restrict__ C, const int* __restrict__ tbl,
    int M, int K, int N)
{
    (void)M;
    __shared__ double As[16][LDD];   // As[k][m]
    __shared__ double Bs[16][LDD];   // Bs[k][n]

    const int tid  = threadIdx.x;
    const int lane = tid & 63;
    const int wv   = tid >> 6;
    const int m0   = wv << 4;

    const int* tl = tbl + lane * 12;
    const int mA = tl[0], kA = tl[1], nB = tl[2], kB = tl[3];
    int iT[4], jT[4];
#pragma unroll
    for (int r = 0; r < 4; ++r) { iT[r] = tl[4 + r]; jT[r] = tl[8 + r]; }

    const int row0 = blockIdx.y * 64;
    const int col0 = blockIdx.x * 64;

    const int ra = tid >> 2;          // A-stage row 0..63
    const int ka = (tid & 3) << 2;    // A-stage k 0,4,8,12
    const int kb = tid >> 4;          // B-stage k 0..15
    const int cb = (tid & 15) << 2;   // B-stage col 0..60

    const size_t aoff = (size_t)(row0 + ra) * K + ka;
    const double* Ar0 = A0g + aoff;
    const double* Ar1 = A1g + aoff;
    const double* Ar2 = A2g + aoff;
    const int cbase = col0 + cb;

    f64x4 acc[4];
#pragma unroll
    for (int j = 0; j < 4; ++j) acc[j] = (f64x4){0.0, 0.0, 0.0, 0.0};

    const int KT = 3 * K;
    double av[4];
    double2 bv0 = {0.0, 0.0}, bv1 = {0.0, 0.0};
    loadA4(Ar0, av);
    if (cbase < N) {
        const double* Brow = B0g + (size_t)kb * N + cbase;
        bv0 = *(const double2*)Brow;
        bv1 = *(const double2*)(Brow + 2);
    }

    for (int kt = 0; kt < KT; kt += 16) {
        __syncthreads();
        As[ka + 0][ra] = av[0]; As[ka + 1][ra] = av[1];
        As[ka + 2][ra] = av[2]; As[ka + 3][ra] = av[3];
        *(double2*)&Bs[kb][cb]     = bv0;
        *(double2*)&Bs[kb][cb + 2] = bv1;
        __syncthreads();

        // prefetch next k-tile (may cross matrix boundary)
        const int nt = kt + 16;
        if (nt < KT) {
            const int m    = (nt >= 2 * K) ? 2 : ((nt >= K) ? 1 : 0);
            const int koff = nt - m * K;
            const double* Ap = (m == 0) ? Ar0 : ((m == 1) ? Ar1 : Ar2);
            const double* Bp = (m == 0) ? B0g : ((m == 1) ? B1g : B2g);
            loadA4(Ap + koff, av);
            if (cbase < N) {
                const double* Brow = Bp + (size_t)(koff + kb) * N + cbase;
                bv0 = *(const double2*)Brow;
                bv1 = *(const double2*)(Brow + 2);
            }
        }

#pragma unroll
        for (int kq = 0; kq < 4; ++kq) {
            const double a = As[(kq << 2) + kA][m0 + mA];
#pragma unroll
            for (int j = 0; j < 4; ++j) {
                const double b = Bs[(kq << 2) + kB][(j << 4) + nB];
                acc[j] = __builtin_amdgcn_mfma_f64_16x16x4f64(a, b, acc[j], 0, 0, 0);
            }
        }
    }

#pragma unroll
    for (int j = 0; j < 4; ++j) {
#pragma unroll
        for (int r = 0; r < 4; ++r) {
            const int c = col0 + (j << 4) + jT[r];
            if (c < N) {
                const int rr = row0 + m0 + iT[r];
                C[(size_t)rr * N + c] = acc[j][r];
            }
        }
    }
}

// ---------------------------------------------------------------------------
// fp64 MFMA GEMM, 64x32 N-split variant (big L0/L1 GEMMs). R7-measured best
// total. Grid 1536 = 6 blocks/CU. Bit-identical k-summation order.
// ---------------------------------------------------------------------------
__global__ __launch_bounds__(256) void gemm_f64n(
    const float* __restrict__ A, const double* __restrict__ Bg, double* __restrict__ Cg,
    const int* __restrict__ tbl,
    int M, int K, int N, long long sB, long long sC)
{
    const double* B = Bg + (size_t)blockIdx.z * sB;
    double*       C = Cg + (size_t)blockIdx.z * sC;

    __shared__ double As[16][66];   // As[k][m]
    __shared__ double Bs[16][34];   // Bs[k][n], 32 cols + pad

    const int tid  = threadIdx.x;
    const int lane = tid & 63;
    const int wv   = tid >> 6;       // wave 0..3 -> rows 16*wv..16*wv+15
    const int m0   = wv << 4;

    const int* tl = tbl + lane * 12;
    const int mA = tl[0], kA = tl[1], nB = tl[2], kB = tl[3];
    int iT[4], jT[4];
#pragma unroll
    for (int r = 0; r < 4; ++r) { iT[r] = tl[4 + r]; jT[r] = tl[8 + r]; }

    const int row0 = blockIdx.y * 64;
    const int col0 = blockIdx.x * 32;

    const int ra = tid >> 2;          // A-stage row 0..63
    const int ka = (tid & 3) << 2;    // A-stage k 0,4,8,12
    const int kb = tid >> 4;          // B-stage k 0..15
    const int cb = (tid & 15) << 1;   // B-stage col 0,2,..,30

    const float* Arow = A + (size_t)(row0 + ra) * K + ka;
    const int cbase = col0 + cb;

    f64x4 acc[2];
#pragma unroll
    for (int j = 0; j < 2; ++j) acc[j] = (f64x4){0.0, 0.0, 0.0, 0.0};

    double av[4];
    double2 bv = {0.0, 0.0};
    loadA4(Arow, av);
    if (cbase < N) bv = *(const double2*)(B + (size_t)kb * N + cbase);

    for (int k0 = 0; k0 < K; k0 += 16) {
        __syncthreads();
        As[ka + 0][ra] = av[0]; As[ka + 1][ra] = av[1];
        As[ka + 2][ra] = av[2]; As[ka + 3][ra] = av[3];
        *(double2*)&Bs[kb][cb] = bv;
        __syncthreads();

        // prefetch k0+16 (overlaps MFMA block)
        if (k0 + 16 < K) {
            loadA4(Arow + k0 + 16, av);
            if (cbase < N) bv = *(const double2*)(B + (size_t)(k0 + 16 + kb) * N + cbase);
        }

#pragma unroll
        for (int kq = 0; kq < 4; ++kq) {
            const double a = As[(kq << 2) + kA][m0 + mA];
#pragma unroll
            for (int j = 0; j < 2; ++j) {
                const double b = Bs[(kq << 2) + kB][(j << 4) + nB];
                acc[j] = __builtin_amdgcn_mfma_f64_16x16x4f64(a, b, acc[j], 0, 0, 0);
            }
        }
    }

#pragma unroll
    for (int j = 0; j < 2; ++j) {
#pragma unroll
        for (int r = 0; r < 4; ++r) {
            const int c = col0 + (j << 4) + jT[r];
            if (c < N) {
                const int rr = row0 + m0 + iT[r];
                C[(size_t)rr * N + c] = acc[j][r];
            }
        }
    }
}

// ---------------------------------------------------------------------------
// Aux kernels. Activation layout: [g=4][node][b=8][C].
// ---------------------------------------------------------------------------
__global__ void zero_k(float* __restrict__ p, int n) {
    int i = blockIdx.x * blockDim.x + threadIdx.x;
    if (i < n) p[i] = 0.f;
}

__global__ void cast16_k(const float* __restrict__ s, f16* __restrict__ d, int n) {
    int i = blockIdx.x * blockDim.x + threadIdx.x;
    if (i < n) d[i] = (f16)s[i];
}

// x [32][3072][32] fp32 -> XT64 [g][n][bi][32] fp64
__global__ void regroup_in64_k(const float* __restrict__ x, double* __restrict__ XT, int total) {
    int i = blockIdx.x * blockDim.x + threadIdx.x;
    if (i >= total) return;
    int c = i & 31;
    int t = i >> 5;
    int n = t % 3072;
    int b = t / 3072;
    XT[((((size_t)(b >> 3) * 3072 + n) << 3) + (b & 7)) * 32 + c] = (double)x[i];
}

// fp16 combine: wa=w0-w2, wb=w1, wc=2*w2
__global__ void cheb_combine16_k(const float* __restrict__ w, f16* __restrict__ wa,
                                 f16* __restrict__ wb, f16* __restrict__ wc, int n) {
    int i = blockIdx.x * blockDim.x + threadIdx.x;
    if (i >= n) return;
    float w0 = w[i], w1 = w[n + i], w2 = w[2 * n + i];
    wa[i] = (f16)(w0 - w2); wb[i] = (f16)w1; wc[i] = (f16)(2.f * w2);
}
// fp64 combine (encoder)
__global__ void cheb_combine64_k(const float* __restrict__ w, double* __restrict__ wa,
                                 double* __restrict__ wb, double* __restrict__ wc, int n) {
    int i = blockIdx.x * blockDim.x + threadIdx.x;
    if (i >= n) return;
    double w0 = w[i], w1 = w[n + i], w2 = w[2 * n + i];
    wa[i] = w0 - w2; wb[i] = w1; wc[i] = 2.0 * w2;
}

__global__ void transpose_w16_k(const float* __restrict__ w, f16* __restrict__ wt, int R, int Ccol) {
    int i = blockIdx.x * blockDim.x + threadIdx.x;
    if (i >= R * Ccol) return;
    int r = i / Ccol, c = i - r * Ccol;
    wt[(size_t)c * R + r] = (f16)w[i];
}
__global__ void transpose_w64_k(const float* __restrict__ w, double* __restrict__ wt, int R, int Ccol) {
    int i = blockIdx.x * blockDim.x + threadIdx.x;
    if (i >= R * Ccol) return;
    int r = i / Ccol, c = i - r * Ccol;
    wt[(size_t)c * R + r] = (double)w[i];
}

// fp32 BN (stats; apply in-place + optional f16 mirror)
__global__ void bn_reduce_k(const float* __restrict__ X, float* __restrict__ stats,
                            int rows, int ld, int off) {
    int c = threadIdx.x;
    float s = 0.f, s2 = 0.f;
    for (int r = blockIdx.x; r < rows; r += gridDim.x) {
        float v = X[(size_t)r * ld + off + c];
        s += v; s2 += v * v;
    }
    atomicAdd(&stats[c], s);
    atomicAdd(&stats[256 + c], s2);
}
__global__ void bn_apply_k(float* X, const float* __restrict__ stats,
                           const float* __restrict__ g, const float* __restrict__ be,
                           const float* rbias, f16* mirror,
                           int total, int C, float invN, int ld, int off) {
    int i = blockIdx.x * blockDim.x + threadIdx.x;
    if (i >= total) return;
    int c = i % C;
    int row = i / C;
    size_t a = (size_t)row * ld + off + c;
    float mu = stats[c] * invN;
    float var = stats[256 + c] * invN - mu * mu;
    float sc = g[c] * rsqrtf(var + 1e-5f);
    float v = (X[a] - mu) * sc + be[c];
    v = fmaxf(v, 0.f);
    if (rbias) v += rbias[c];
    X[a] = v;
    if (mirror) mirror[a] = (f16)v;
}

// fp64 BN (encoder)
__global__ void bn_reduce64_k(const double* __restrict__ X, double* __restrict__ stats,
                              int rows, int ld) {
    int c = threadIdx.x;
    double s = 0.0, s2 = 0.0;
    for (int r = blockIdx.x; r < rows; r += gridDim.x) {
        double v = X[(size_t)r * ld + c];
        s += v; s2 += v * v;
    }
    atomicAdd(&stats[c], s);
    atomicAdd(&stats[256 + c], s2);
}
__global__ void bn_apply64_k(double* X, const double* __restrict__ stats,
                             const float* __restrict__ g, const float* __restrict__ be,
                             const float* rbias, int total, int C, double invN) {
    int i = blockIdx.x * blockDim.x + threadIdx.x;
    if (i >= total) return;
    int c = i % C;
    double mu = stats[c] * invN;
    double var = stats[256 + c] * invN - mu * mu;
    double sc = (double)g[c] / sqrt(var + 1e-5);
    double v = (X[i] - mu) * sc + (double)be[c];
    v = v > 0.0 ? v : 0.0;
    if (rbias) v += (double)rbias[c];
    X[i] = v;
}

// fp64 e1 [row][128] -> CATh high half (f16, ld 256, off 128)
__global__ void cast_e1_k(const double* __restrict__ E1, f16* __restrict__ cat, int total) {
    int i = blockIdx.x * blockDim.x + threadIdx.x;
    if (i >= total) return;
    int c = i & 127;
    int row = i >> 7;
    cat[(size_t)row * 256 + 128 + c] = (f16)E1[i];
}

// pool 4 consecutive nodes of fp64 e1 -> Ph f16 [g][q][b][128], IDX node index
__global__ void pool4_64_k(const double* __restrict__ e1, f16* __restrict__ p,
                           int* __restrict__ idx, int total) {
    int i = blockIdx.x * blockDim.x + threadIdx.x;
    if (i >= total) return;
    int c = i & 127;
    int t = i >> 7;
    int b = t & 7;
    t >>= 3;
    int q = t % 768;
    int g = t / 768;
    size_t base = ((((size_t)g * 3072 + 4 * q) << 3) + b) * 128 + c;
    double best = e1[base];
    int bj = 0;
#pragma unroll
    for (int j = 1; j < 4; ++j) {
        double v = e1[base + (size_t)j * 1024];
        if (v > best) { best = v; bj = j; }   // strict >: first occurrence (jnp.argmax)
    }
    p[i] = (f16)best;
    idx[i] = 4 * q + bj;
}

// scatter e2 (fp32) into CATh low half (f16)
__global__ void unpool_cat_k(const float* __restrict__ e2, const int* __restrict__ idx,
                             f16* __restrict__ cat, int total) {
    int i = blockIdx.x * blockDim.x + threadIdx.x;
    if (i >= total) return;
    int c = i & 127;
    int t = i >> 7;
    int b = t & 7;
    t >>= 3;
    int q = t % 768;
    int g = t / 768;
    f16 val = (f16)e2[i];
    int id = idx[i];
    size_t base = ((((size_t)g * 3072 + 4 * q) << 3) + b) * 256 + c;
#pragma unroll
    for (int j = 0; j < 4; ++j)
        cat[base + (size_t)j * 2048] = (4 * q + j == id) ? val : (f16)0.f;
}

// O [g][n][bi][8] fp32 -> out [B][N][8], + bias
__global__ void transpose_out_k(const float* __restrict__ O, const float* __restrict__ bias,
                                float* __restrict__ out, int total) {
    int i = blockIdx.x * blockDim.x + threadIdx.x;
    if (i >= total) return;
    int c = i & 7;
    int t = i >> 3;
    int n = t % 3072;
    int b = t / 3072;
    out[i] = O[((((size_t)(b >> 3) * 3072 + n) << 3) + (b & 7)) * 8 + c] + bias[c];
}

// ---------------------------------------------------------------------------
extern "C" void kernel_launch(void* const* d_in, const int* in_sizes, int n_in,
                              void* d_out, int out_size, void* d_ws, size_t ws_size,
                              hipStream_t stream)
{
    (void)in_sizes; (void)n_in; (void)out_size; (void)ws_size;

    const float* x    = (const float*)d_in[0];
    const float* L0   = (const float*)d_in[1];
    const float* L1   = (const float*)d_in[2];
    const float* w11  = (const float*)d_in[3];
    const float* g11  = (const float*)d_in[5];
    const float* be11 = (const float*)d_in[6];
    const float* w13  = (const float*)d_in[7];
    const float* g13  = (const float*)d_in[9];
    const float* be13 = (const float*)d_in[10];
    const float* wr1  = (const float*)d_in[11];
    const float* br1  = (const float*)d_in[12];
    const float* w21  = (const float*)d_in[13];
    const float* g21  = (const float*)d_in[15];
    const float* be21 = (const float*)d_in[16];
    const float* w23  = (const float*)d_in[17];
    const float* g23  = (const float*)d_in[19];
    const float* be23 = (const float*)d_in[20];
    const float* wr2  = (const float*)d_in[21];
    const float* br2  = (const float*)d_in[22];
    const float* uw11 = (const float*)d_in[23];
    const float* ug11 = (const float*)d_in[25];
    const float* ube11= (const float*)d_in[26];
    const float* uw12 = (const float*)d_in[27];
    const float* ug12 = (const float*)d_in[29];
    const float* ube12= (const float*)d_in[30];
    const float* uwr1 = (const float*)d_in[31];
    const float* ubr1 = (const float*)d_in[32];
    const float* uw13 = (const float*)d_in[33];
    const float* ub13 = (const float*)d_in[34];
    float* out = (float*)d_out;

    float* ws = (float*)d_ws;
    size_t off = 0;
    auto alloc = [&](size_t n) { float* p = ws + off; off += (n + 63) & ~(size_t)63; return p; };

    // ---- regions (floats). Total ~224 MiB. ----
    float* R1 = alloc(12582912);   // CATh f16[25165824] | p1: H1 dbl[6291456]
    float* R2 = alloc(25165824);   // D1 fp32 + H64 fp32 + T1h/T2h f16 | p1: E1 dbl[12582912]
    float* R3 = alloc(6291456);    // p1: XT64 dbl[3145728] | p2: H2h f16 then D1h f16
    float* R4 = alloc(6291456);    // p1: T1d dbl[3145728] | p2: Ph f16 + H64h f16
    int*  IDX = (int*)alloc(3145728);  // p1 (with L0f): T2d dbl[3145728]
    float* L0f = alloc(4718592);   // p2: L0h f16[9437184]
    float* L1f = alloc(294912);    // p2: L1h f16[589824]
    float* ST  = alloc(1536);      // fp32 stats [0..512), fp64 stats [512..1536)
    int*  TBL  = (int*)alloc(768); // f64-MFMA layout table (64 lanes x 12 ints)

    // f16 weights
    f16* wa21h = (f16*)alloc(12288); f16* wb21h = (f16*)alloc(12288); f16* wc21h = (f16*)alloc(12288);
    f16* wa23h = (f16*)alloc(12288); f16* wb23h = (f16*)alloc(12288); f16* wc23h = (f16*)alloc(12288);
    f16* wau11h = (f16*)alloc(16384); f16* wbu11h = (f16*)alloc(16384); f16* wcu11h = (f16*)alloc(16384);
    f16* wau12h = (f16*)alloc(4096);  f16* wbu12h = (f16*)alloc(4096);  f16* wcu12h = (f16*)alloc(4096);
    f16* wau13h = (f16*)alloc(256);   f16* wbu13h = (f16*)alloc(256);   f16* wcu13h = (f16*)alloc(256);
    f16* wr2Th  = (f16*)alloc(8192);
    f16* uwr1Th = (f16*)alloc(8192);

    // fp64 weights (encoder)
    double* wa11_64 = (double*)alloc(4096);
    double* wb11_64 = (double*)alloc(4096);
    double* wc11_64 = (double*)alloc(4096);
    double* wa13_64 = (double*)alloc(16384);
    double* wb13_64 = (double*)alloc(16384);
    double* wc13_64 = (double*)alloc(16384);
    double* wr1T_64 = (double*)alloc(8192);

    // ---- aliases ----
    f16*    CATh = (f16*)R1;
    double* H1   = (double*)R1;
    float*  D1   = R2;                       // [g][n][b][128] fp32
    float*  H2   = R2;                       // [g][q][b][192] fp32
    float*  Y3   = R2 + 4718592;             // [g][q][b][128] fp32
    float*  O    = R2;                       // final [g][n][b][8] fp32
    float*  H64  = R2 + 12582912;            // [g][n][b][64] fp32
    f16*    T1h  = (f16*)(R2 + 18874368);    // f16[6291456]
    f16*    T2h  = (f16*)(R2 + 22020096);    // f16[6291456]
    f16*    TCMB = T1h;                      // T1h+T2h contiguous: f16[12582912] (dec1 z=4 merge)
    double* E1   = (double*)R2;              // dbl[12582912] spans R2
    double* XT64 = (double*)R3;
    f16*    H2h  = (f16*)R3;                 // early phase-2
    f16*    D1h  = (f16*)R3;                 // late phase-2 (H2h dead)
    double* T1d  = (double*)R4;              // dbl[3145728]
    double* T2d  = (double*)IDX;             // dbl[3145728] spanning IDX + L0f front half
    f16*    Ph   = (f16*)R4;                 // f16[3145728] (phase 2)
    f16*    H64h = (f16*)(R4 + 1572864);     // f16[6291456] (phase 2)
    f16*    L0h  = (f16*)L0f;
    f16*    L1h  = (f16*)L1f;
    double* ST64 = (double*)(ST + 512);
    // reassociated-decoder scratch (all dead-slot reuse, no new allocs):
    float*  RFa  = H64;                      // final-conv R fp32
    float*  RFb  = R2;                       // dec1/dec2 R fp32 (D1-slot time-share)

    auto gh = [&](int mode, const f16* A, const f16* B, void* C, int M, int K, int N,
                  int ldc, long long sB, long long sC, int z, int ks) {
        dim3 grid((N + 127) / 128, M / 128, z * ks);
        if (mode == 0)      gemm_h<0><<<grid, 256, 0, stream>>>(A, B, C, M, K, N, ldc, sB, sC, ks);
        else if (mode == 1) gemm_h<1><<<grid, 256, 0, stream>>>(A, B, C, M, K, N, ldc, sB, sC, ks);
        else if (mode == 2) gemm_h<2><<<grid, 256, 0, stream>>>(A, B, C, M, K, N, ldc, sB, sC, ks);
        else                gemm_h<3><<<grid, 256, 0, stream>>>(A, B, C, M, K, N, ldc, sB, sC, ks);
    };
    // big L GEMMs: 64x32 N-split tile (grid 1536 = 6 blocks/CU)
    auto gemm64f = [&](const float* A, const double* B, double* C, int M, int K, int N,
                       long long sB, long long sC, int z) {
        dim3 grid((N + 31) / 32, M / 64, z);
        gemm_f64n<<<grid, 256, 0, stream>>>(A, B, C, TBL, M, K, N, sB, sC);
    };
    auto gemm64d = [&](const double* A, const double* B, double* C, int M, int K, int N, int accum) {
        dim3 grid((N + 63) / 64, M / 64);
        gemm_f64<double><<<grid, 256, 0, stream>>>(A, B, C, TBL, M, K, N, 0, 0, accum);
    };
    auto gemm64w3 = [&](const double* A0, const double* A1, const double* A2,
                        const double* B0, const double* B1, const double* B2,
                        double* C, int M, int K, int N) {
        dim3 grid((N + 63) / 64, M / 64);
        gemm_f64w3<<<grid, 256, 0, stream>>>(A0, A1, A2, B0, B1, B2, C, TBL, M, K, N);
    };
    auto bn = [&](float* X, int rows, int C, int ld, int offc,
                  const float* gp, const float* bep, const float* rbias, f16* mirror) {
        zero_k<<<2, 256, 0, stream>>>(ST, 512);
        bn_reduce_k<<<384, C, 0, stream>>>(X, ST, rows, ld, offc);
        int total = rows * C;
        bn_apply_k<<<(total + 255) / 256, 256, 0, stream>>>(
            X, ST, gp, bep, rbias, mirror, total, C, 1.f / (float)rows, ld, offc);
    };
    auto bn64 = [&](double* X, int rows, int C,
                    const float* gp, const float* bep, const float* rbias) {
        zero_k<<<4, 256, 0, stream>>>(ST + 512, 1024);
        bn_reduce64_k<<<384, C, 0, stream>>>(X, ST64, rows, C);
        int total = rows * C;
        bn_apply64_k<<<(total + 255) / 256, 256, 0, stream>>>(
            X, ST64, gp, bep, rbias, total, C, 1.0 / (double)rows);
    };
    auto comb16 = [&](const float* w, f16* a, f16* b, f16* c, int n) {
        cheb_combine16_k<<<(n + 255) / 256, 256, 0, stream>>>(w, a, b, c, n);
    };

    // ---- f64-MFMA layout probe (must precede all gemm_f64 launches) ----
    probe_f64_k<<<1, 64, 0, stream>>>(TBL);

    // ---- fp64 weight prep + input regroup ----
    cheb_combine64_k<<<8, 256, 0, stream>>>(w11, wa11_64, wb11_64, wc11_64, 2048);
    cheb_combine64_k<<<32, 256, 0, stream>>>(w13, wa13_64, wb13_64, wc13_64, 8192);
    transpose_w64_k<<<16, 256, 0, stream>>>(wr1, wr1T_64, 128, 32);
    regroup_in64_k<<<12288, 256, 0, stream>>>(x, XT64, 3145728);

    // ==== PHASE 1 (fp64 MFMA): encoder to e1, exact argmax ====
    // conv1: 32 -> 64, z=4 batched (T1d/T2d = [4][3072][256] dbl)
    // 3-term fused weight GEMM (register accumulation, no C RMW).
    gemm64f(L0, XT64, T1d, 3072, 3072, 256, 786432, 786432, 4);
    gemm64f(L0, T1d, T2d, 3072, 3072, 256, 786432, 786432, 4);
    gemm64w3(XT64, T1d, T2d, wa11_64, wb11_64, wc11_64, H1, 98304, 32, 64);
    bn64(H1, 98304, 64, g11, be11, nullptr);                 // h1

    // conv2: 64 -> 128, two z=2 halves (T1d/T2d = [2][3072][512] dbl)
    for (int h = 0; h < 2; ++h) {
        const double* Hh = H1 + (size_t)h * 3145728;
        double*       Eh = E1 + (size_t)h * 6291456;
        gemm64f(L0, Hh, T1d, 3072, 3072, 512, 1572864, 1572864, 2);
        gemm64f(L0, T1d, T2d, 3072, 3072, 512, 1572864, 1572864, 2);
        gemm64w3(Hh, T1d, T2d, wa13_64, wb13_64, wc13_64, Eh, 49152, 64, 128);
    }
    bn64(E1, 98304, 128, g13, be13, br1);
    gemm64d(XT64, wr1T_64, E1, 98304, 32, 128, 1);           // e1 (fp64, RMW residual)

    // ---- f16 weight prep (delayed: L0f/IDX regions were phase-1 scratch) ----
    comb16(w21,  wa21h,  wb21h,  wc21h,  24576);
    comb16(w23,  wa23h,  wb23h,  wc23h,  24576);
    comb16(uw11, wau11h, wbu11h, wcu11h, 32768);
    comb16(uw12, wau12h, wbu12h, wcu12h, 8192);
    comb16(uw13, wau13h, wbu13h, wcu13h, 512);
    transpose_w16_k<<<64, 256, 0, stream>>>(wr2, wr2Th, 128, 128);
    transpose_w16_k<<<64, 256, 0, stream>>>(uwr1, uwr1Th, 64, 256);
    cast16_k<<<36864, 256, 0, stream>>>(L0, L0h, 9437184);
    cast16_k<<<2304, 256, 0, stream>>>(L1, L1h, 589824);

    // transition: pool on fp64; CATh high = f16(e1)
    pool4_64_k<<<12288, 256, 0, stream>>>(E1, Ph, IDX, 3145728);
    cast_e1_k<<<49152, 256, 0, stream>>>(E1, CATh, 12582912);
    // E1 / XT64 / H1 / T1d / T2d dead from here.

    // ==== PHASE 2 (fp16 MFMA) ====
    // L2 conv1: 128 -> 192. R11: reverted to R9's direct form (R10's K-split
    // regressed: zero/cast overhead on cache-resident small GEMMs).
    gh(0, L1h, Ph, T1h, 768, 768, 1024, 1024, 786432, 786432, 4, 1);
    gh(0, L1h, T1h, T2h, 768, 768, 1024, 1024, 786432, 786432, 4, 1);
    gh(1, Ph,  wa21h, H2, 24576, 128, 192, 192, 0, 0, 1, 1);
    gh(2, T1h, wb21h, H2, 24576, 128, 192, 192, 0, 0, 1, 1);
    gh(2, T2h, wc21h, H2, 24576, 128, 192, 192, 0, 0, 1, 1);
    bn(H2, 24576, 192, 192, 0, g21, be21, nullptr, H2h);     // h2 (+f16 mirror)

    // L2 conv2: 192 -> 128, + residual -> e2 (Y3)
    gh(0, L1h, H2h, T1h, 768, 768, 1536, 1536, 1179648, 1179648, 4, 1);
    gh(0, L1h, T1h, T2h, 768, 768, 1536, 1536, 1179648, 1179648, 4, 1);
    gh(1, H2h, wa23h, Y3, 24576, 192, 128, 128, 0, 0, 1, 1);
    gh(2, T1h, wb23h, Y3, 24576, 192, 128, 128, 0, 0, 1, 1);
    gh(2, T2h, wc23h, Y3, 24576, 192, 128, 128, 0, 0, 1, 1);
    bn(Y3, 24576, 128, 128, 0, g23, be23, br2, nullptr);
    gh(2, Ph, wr2Th, Y3, 24576, 128, 128, 128, 0, 0, 1, 1);  // e2

    // unpool into CATh low (f16)
    unpool_cat_k<<<12288, 256, 0, stream>>>(Y3, IDX, CATh, 3145728);

    // dec conv1: 256 -> 128, REASSOCIATED, single z=4 pass (R8, 768-block
    // balanced). Buffers: P2->TCMB, R->D1 slot, Rh->TCMB, D->D1 slot.
    gh(0, CATh, wcu11h, TCMB, 98304, 256, 128, 128, 0, 0, 1, 1);            // P2 = cat*Wc (f16)
    gh(1, CATh, wbu11h, RFb, 98304, 256, 128, 128, 0, 0, 1, 1);             // R  = cat*Wb (f32)
    gh(2, L0h, TCMB, RFb, 3072, 3072, 1024, 1024, 3145728, 3145728, 4, 1);  // R += L*P2 (768 blk)
    cast16_k<<<49152, 256, 0, stream>>>(RFb, TCMB, 12582912);               // Rh = f16(R), P2 dead
    gh(1, CATh, wau11h, D1, 98304, 256, 128, 128, 0, 0, 1, 1);              // D  = cat*Wa (over R)
    gh(2, L0h, TCMB, D1, 3072, 3072, 1024, 1024, 3145728, 3145728, 4, 1);   // D += L*Rh
    bn(D1, 98304, 128, 128, 0, ug11, ube11, nullptr, D1h);   // d1 (+f16 mirror)

    // dec conv2: 128 -> 64, REASSOCIATED. R9: L-GEMMs K-split x2 via MODE 3
    // atomic (384 -> 768 blocks; weight GEMM stores first, no pre-zero).
    gh(0, D1h, wcu12h, T2h, 98304, 128, 64, 64, 0, 0, 1, 1);                // P2 = d1*Wc
    gh(1, D1h, wbu12h, RFb, 98304, 128, 64, 64, 0, 0, 1, 1);                // R  = d1*Wb
    gh(3, L0h, T2h, RFb, 3072, 3072, 512, 512, 1572864, 1572864, 4, 2);     // R += L*P2 (atomic)
    cast16_k<<<24576, 256, 0, stream>>>(RFb, T1h, 6291456);                 // Rh
    gh(1, D1h, wau12h, H64, 98304, 128, 64, 64, 0, 0, 1, 1);                // H64 = d1*Wa
    gh(3, L0h, T1h, H64, 3072, 3072, 512, 512, 1572864, 1572864, 4, 2);     // H64 += L*R (atomic)
    bn(H64, 98304, 64, 64, 0, ug12, ube12, ubr1, nullptr);
    gh(2, CATh, uwr1Th, H64, 98304, 256, 64, 64, 0, 0, 1, 1); // d2 = bn + residual
    cast16_k<<<24576, 256, 0, stream>>>(H64, H64h, 6291456);  // d2 f16 mirror (H64 fp32 dead)

    // final conv: 64 -> 8, REASSOCIATED. R9: L-GEMMs K-split x8 via MODE 3
    // atomic (96 -> 768 blocks; Ks=384).
    gh(0, H64h, wcu13h, T2h, 98304, 64, 8, 8, 0, 0, 1, 1);                  // P2 = d2*Wc
    gh(1, H64h, wbu13h, RFa, 98304, 64, 8, 8, 0, 0, 1, 1);                  // R  = d2*Wb
    gh(3, L0h, T2h, RFa, 3072, 3072, 64, 64, 196608, 196608, 4, 8);         // R += L*P2 (atomic)
    cast16_k<<<3072, 256, 0, stream>>>(RFa, T1h, 786432);                   // Rh
    gh(1, H64h, wau13h, O, 98304, 64, 8, 8, 0, 0, 1, 1);                    // O  = d2*Wa
    gh(3, L0h, T1h, O, 3072, 3072, 64, 64, 196608, 196608, 4, 8);           // O += L*R (atomic)

    transpose_out_k<<<3072, 256, 0, stream>>>(O, ub13, out, 786432);
}